// Round 3
// baseline (36.919 us; speedup 1.0000x reference)
//
#include <hip/hip_runtime.h>
#include <math.h>

#define NC 80
#define NA 3
#define BATCH 16
#define NGT 32
#define IOU_THR 0.5f
#define FEPS 1e-7f

#define ASSIGN_BLOCKS 48          // one per (batch, scale)
#define OBJ_BLOCKS 512
#define OBJ_TOTAL 403200          // 307200 + 76800 + 19200 obj logits
#define S0_END 307200
#define S1_END 384000

// ws layout (floats), every slot written unconditionally each call:
//   assign block blk (0..47):  ws_f[8*blk + {0:box,1:nv,2:cls,3:obj_corr,4:np}]
//   obj block j (0..511):      ws_f[OBJ_PART + 4*j + si]  (3 scales)
#define OBJ_PART 384              // 48*8

__device__ __forceinline__ float bce_f(float x, float t) {
    return fmaxf(x, 0.f) - x * t + log1pf(expf(-fabsf(x)));
}

__global__ __launch_bounds__(256) void main_kernel(
    const float* __restrict__ p0, const float* __restrict__ p1, const float* __restrict__ p2,
    const float* __restrict__ a0, const float* __restrict__ a1, const float* __restrict__ a2,
    const float* __restrict__ gt_boxes, const int* __restrict__ gt_labels,
    float* __restrict__ ws_f)
{
    const int bid = blockIdx.x;
    const int t = threadIdx.x;
    __shared__ float red[4][4];

    if (bid >= ASSIGN_BLOCKS) {
        // ================= obj noobj-base sweep =================
        const int j = bid - ASSIGN_BLOCKS;
        float acc0 = 0.f, acc1 = 0.f, acc2 = 0.f;
        for (int g = j * 256 + t; g < OBJ_TOTAL; g += OBJ_BLOCKS * 256) {
            const float* p; int local;
            if (g < S0_END)      { p = p0; local = g; }
            else if (g < S1_END) { p = p1; local = g - S0_END; }
            else                 { p = p2; local = g - S1_END; }
            float x = p[(size_t)local * (5 + NC) + 4];
            float v = 0.5f * bce_f(x, 0.f);
            if (g < S0_END) acc0 += v; else if (g < S1_END) acc1 += v; else acc2 += v;
        }
        #pragma unroll
        for (int off = 32; off; off >>= 1) {
            acc0 += __shfl_down(acc0, off);
            acc1 += __shfl_down(acc1, off);
            acc2 += __shfl_down(acc2, off);
        }
        int lane = t & 63, wv = t >> 6;
        if (lane == 0) { red[0][wv] = acc0; red[1][wv] = acc1; red[2][wv] = acc2; }
        __syncthreads();
        if (t < 3)
            ws_f[OBJ_PART + 4 * j + t] = red[t][0] + red[t][1] + red[t][2] + red[t][3];
        return;
    }

    // ================= fused assignment + positive losses =================
    const int si = bid % 3;
    const int b  = bid / 3;
    const int W  = 80 >> si;
    const int HW = W * W;
    const float s = (float)(8 << si);
    const float* anch = (si == 0) ? a0 : (si == 1) ? a1 : a2;
    const float* p    = (si == 0) ? p0 : (si == 1) ? p1 : p2;

    __shared__ float gtb[NGT][4];
    __shared__ int   gflat[NGT];
    __shared__ float giou[NA][NGT];
    __shared__ float gcand[NA][NGT];
    __shared__ unsigned char gpos[NA][NGT];
    __shared__ unsigned char gisb[NA][NGT];
    __shared__ int wflag[NA * NGT];
    __shared__ int wlist[NA * NGT];
    __shared__ int s_wn;

    if (t < 128) gtb[t >> 2][t & 3] = gt_boxes[b * NGT * 4 + t];
    __syncthreads();

    if (t < NGT) {
        float x1 = gtb[t][0], y1 = gtb[t][1], x2 = gtb[t][2], y2 = gtb[t][3];
        float gcx = (x1 + x2) * 0.5f, gcy = (y1 + y2) * 0.5f;
        int gx = (int)(gcx / s); gx = min(max(gx, 0), W - 1);
        int gy = (int)(gcy / s); gy = min(max(gy, 0), W - 1);
        gflat[t] = gy * W + gx;
    }
    __syncthreads();

    if (t < NA * NGT) {
        int a = t >> 5, n = t & 31;
        int flat = gflat[n];
        const float* ap = anch + ((size_t)a * HW + flat) * 4;
        float acx = ap[0], acy = ap[1], aw = ap[2], ah = ap[3];
        float ax1 = acx - aw * 0.5f, ay1 = acy - ah * 0.5f;
        float ax2 = acx + aw * 0.5f, ay2 = acy + ah * 0.5f;
        float x1 = gtb[n][0], y1 = gtb[n][1], x2 = gtb[n][2], y2 = gtb[n][3];
        float iw = fmaxf(fminf(x2, ax2) - fmaxf(x1, ax1), 0.f);
        float ih = fmaxf(fminf(y2, ay2) - fmaxf(y1, ay1), 0.f);
        float inter = iw * ih;
        float a_gt = (x2 - x1) * (y2 - y1);
        float a_an = aw * ah;
        giou[a][n] = inter / (a_gt + a_an - inter + FEPS);
    }
    __syncthreads();

    if (t < NA * NGT) {
        int a = t >> 5, n = t & 31;
        float i0 = giou[0][n], i1 = giou[1][n], i2 = giou[2][n];
        bool has = (i0 > IOU_THR) || (i1 > IOU_THR) || (i2 > IOU_THR);
        int amax = 0; float bv = i0;                    // first-max like jnp.argmax
        if (i1 > bv) { bv = i1; amax = 1; }
        if (i2 > bv) { bv = i2; amax = 2; }
        float iou = giou[a][n];
        bool ps = has ? (iou > IOU_THR) : (a == amax);
        gpos[a][n] = ps ? 1 : 0;
        gcand[a][n] = ps ? iou : -1.0f;
    }
    __syncthreads();

    if (t < NA * NGT) {
        int a = t >> 5, n = t & 31;
        int flat = gflat[n];
        float best = -1.0f;                             // scatter-max init
        for (int m = 0; m < NGT; ++m)
            if (gflat[m] == flat) best = fmaxf(best, gcand[a][m]);
        gisb[a][n] = (gpos[a][n] && gcand[a][n] >= best) ? 1 : 0;
    }
    __syncthreads();

    if (t < NA * NGT) {
        int a = t >> 5, n = t & 31;
        int wf = -1;
        if (gisb[a][n]) {
            int flat = gflat[n];
            bool first = true;                          // win = min gt index among isb
            for (int m = 0; m < n; ++m)
                if (gflat[m] == flat && gisb[a][m]) { first = false; break; }
            if (first) wf = flat | (a << 13) | (n << 19);
        }
        wflag[t] = wf;
    }
    __syncthreads();
    if (t == 0) {
        int wn = 0;
        #pragma unroll 4
        for (int m = 0; m < NA * NGT; ++m)
            if (wflag[m] >= 0) wlist[wn++] = wflag[m];
        s_wn = wn;
    }
    __syncthreads();
    const int wn = s_wn;

    float v_box = 0.f, v_nv = 0.f, v_cls = 0.f, v_obj = 0.f;
    const int g16 = t >> 4, l16 = t & 15;
    for (int base = 0; base < wn; base += 16) {
        int cell = base + g16;
        if (cell < wn) {
            int e = wlist[cell];
            int flat = e & 0x1FFF;
            int a = (e >> 13) & 7;
            int n = (e >> 19) & 31;
            const float* pred = p + (size_t)((b * NA + a) * HW + flat) * (5 + NC);

            // cls BCE: 5 coalesced channels per lane of the 16-group
            int label = gt_labels[b * NGT + n];
            float csum = 0.f;
            #pragma unroll
            for (int jj = 0; jj < 5; ++jj) {
                int c = l16 + 16 * jj;
                float x = pred[5 + c];
                csum += bce_f(x, (c == label) ? 1.f : 0.f);
            }
            #pragma unroll
            for (int m = 8; m; m >>= 1) csum += __shfl_xor(csum, m);

            // decode + ciou (redundant on 16 lanes; lane 0 accumulates)
            const float* ap = anch + ((size_t)a * HW + flat) * 4;
            float acx = ap[0], acy = ap[1], aw = ap[2], ah = ap[3];
            float s0 = 1.f / (1.f + expf(-pred[0]));
            float s1 = 1.f / (1.f + expf(-pred[1]));
            float s2 = 1.f / (1.f + expf(-pred[2]));
            float s3 = 1.f / (1.f + expf(-pred[3]));
            float cx = acx + (s0 * 2.f - 0.5f) * s;
            float cy = acy + (s1 * 2.f - 0.5f) * s;
            float pw = aw * (s2 * 2.f) * (s2 * 2.f);
            float ph = ah * (s3 * 2.f) * (s3 * 2.f);
            float b1x1 = cx - pw * 0.5f, b1y1 = cy - ph * 0.5f;
            float b1x2 = cx + pw * 0.5f, b1y2 = cy + ph * 0.5f;
            float b2x1 = gtb[n][0], b2y1 = gtb[n][1];
            float b2x2 = gtb[n][2], b2y2 = gtb[n][3];

            float w1 = b1x2 - b1x1, h1 = b1y2 - b1y1;
            float w2 = b2x2 - b2x1, h2 = b2y2 - b2y1;
            float iw = fmaxf(fminf(b1x2, b2x2) - fmaxf(b1x1, b2x1), 0.f);
            float ih = fmaxf(fminf(b1y2, b2y2) - fmaxf(b1y1, b2y1), 0.f);
            float inter = iw * ih;
            float uni = w1 * h1 + w2 * h2 - inter + FEPS;
            float iou = inter / uni;
            float cw = fmaxf(b1x2, b2x2) - fminf(b1x1, b2x1);
            float ch = fmaxf(b1y2, b2y2) - fminf(b1y1, b2y1);
            float c2 = cw * cw + ch * ch + FEPS;
            float dx = b2x1 + b2x2 - b1x1 - b1x2;
            float dy = b2y1 + b2y2 - b1y1 - b1y2;
            float rho2 = (dx * dx + dy * dy) * 0.25f;
            const float PI = 3.14159265358979323846f;
            float dv = atanf(w2 / (h2 + FEPS)) - atanf(w1 / (h1 + FEPS));
            float v = (4.f / (PI * PI)) * dv * dv;
            float alpha = v / (v - iou + (1.f + FEPS));
            float ciou = iou - rho2 / c2 - alpha * v;

            if (l16 == 0) {
                if (isfinite(ciou)) { v_box += 1.f - ciou; v_nv += 1.f; }
                v_cls += csum;
                float ox = pred[4];
                v_obj += bce_f(ox, 1.f) - 0.5f * bce_f(ox, 0.f);
            }
        }
    }

    // block-level reduce, then unconditional partial write (no atomics)
    int lane = t & 63, wv = t >> 6;
    #pragma unroll
    for (int off = 32; off; off >>= 1) {
        v_box += __shfl_down(v_box, off);
        v_nv  += __shfl_down(v_nv,  off);
        v_cls += __shfl_down(v_cls, off);
        v_obj += __shfl_down(v_obj, off);
    }
    if (lane == 0) { red[0][wv] = v_box; red[1][wv] = v_nv; red[2][wv] = v_cls; red[3][wv] = v_obj; }
    __syncthreads();
    if (t == 0) {
        float* slot = ws_f + 8 * bid;
        slot[0] = red[0][0] + red[0][1] + red[0][2] + red[0][3];
        slot[1] = red[1][0] + red[1][1] + red[1][2] + red[1][3];
        slot[2] = red[2][0] + red[2][1] + red[2][2] + red[2][3];
        slot[3] = red[3][0] + red[3][1] + red[3][2] + red[3][3];
        slot[4] = (float)wn;
    }
}

__global__ __launch_bounds__(256) void final_kernel(const float* __restrict__ ws_f,
                                                    float* __restrict__ out)
{
    const int t = threadIdx.x;
    const int wv = t >> 6, lane = t & 63;
    __shared__ float sc[3][5];   // per scale: box, nv, cls, obj, np

    if (wv < 3) {
        const int s = wv;
        float obj = 0.f;
        for (int j = lane; j < OBJ_BLOCKS; j += 64)
            obj += ws_f[OBJ_PART + 4 * j + s];
        float box = 0.f, nv = 0.f, cls = 0.f, np = 0.f;
        if (lane < BATCH) {
            const float* slot = ws_f + 8 * (lane * 3 + s);  // block (b=lane, si=s)
            box = slot[0]; nv = slot[1]; cls = slot[2]; obj += slot[3]; np = slot[4];
        }
        #pragma unroll
        for (int off = 32; off; off >>= 1) {
            box += __shfl_down(box, off);
            nv  += __shfl_down(nv,  off);
            cls += __shfl_down(cls, off);
            obj += __shfl_down(obj, off);
            np  += __shfl_down(np,  off);
        }
        if (lane == 0) {
            sc[s][0] = box; sc[s][1] = nv; sc[s][2] = cls; sc[s][3] = obj; sc[s][4] = np;
        }
    }
    __syncthreads();
    if (t == 0) {
        float bl = 0.f, ol = 0.f, cl = 0.f;
        int tv = 0;
        for (int s = 0; s < 3; ++s) {
            int W = 80 >> s;
            int total = BATCH * NA * W * W;
            float nv = sc[s][1];
            float np = sc[s][4];
            float box_loss = sc[s][0] / fmaxf(nv, 1.f);
            float wsum = np + 0.5f * ((float)total - np);
            float obj_loss = sc[s][3] / (wsum + 1e-6f);
            float cls_loss = sc[s][2] / fmaxf(np * (float)NC, 1.f);
            bl += box_loss; ol += obj_loss; cl += cls_loss; tv += (int)nv;
        }
        if (tv > 0) { bl /= 3.f; cl /= 3.f; }
        ol /= 3.f;
        float total = 0.15f * bl + 5.0f * ol + 0.5f * cl;
        out[0] = isfinite(total) ? total : 0.f;
    }
}

extern "C" void kernel_launch(void* const* d_in, const int* in_sizes, int n_in,
                              void* d_out, int out_size, void* d_ws, size_t ws_size,
                              hipStream_t stream) {
    const float* p0  = (const float*)d_in[0];
    const float* p1  = (const float*)d_in[1];
    const float* p2  = (const float*)d_in[2];
    const float* a0  = (const float*)d_in[3];
    const float* a1  = (const float*)d_in[4];
    const float* a2  = (const float*)d_in[5];
    const float* gtb = (const float*)d_in[6];
    const int*   gtl = (const int*)d_in[7];
    float* out  = (float*)d_out;
    float* ws_f = (float*)d_ws;

    main_kernel<<<ASSIGN_BLOCKS + OBJ_BLOCKS, 256, 0, stream>>>(
        p0, p1, p2, a0, a1, a2, gtb, gtl, ws_f);
    final_kernel<<<1, 256, 0, stream>>>(ws_f, out);
}